// Round 12
// baseline (997.470 us; speedup 1.0000x reference)
//
#include <hip/hip_runtime.h>

typedef unsigned short u16;
typedef unsigned int u32;

typedef __bf16 bf16x8 __attribute__((ext_vector_type(8)));
typedef float f32x4 __attribute__((ext_vector_type(4)));

union FragI { int4 i; bf16x8 b; u16 u[8]; };

__device__ __forceinline__ u16 f2bf(float x) {
  u32 u = __float_as_uint(x);
  u32 r = (u + 0x7fffu + ((u >> 16) & 1u)) >> 16;
  return (u16)r;
}
__device__ __forceinline__ float tanh_fast(float x) {
  float e = __expf(2.0f * x);
  return 1.0f - __fdividef(2.0f, e + 1.0f);
}
__device__ __forceinline__ bf16x8 load_cvt8(const float* __restrict__ p) {
  float4 f0 = *(const float4*)p;
  float4 f1 = *(const float4*)(p + 4);
  union { bf16x8 b; u16 u[8]; } t;
  t.u[0] = f2bf(f0.x); t.u[1] = f2bf(f0.y); t.u[2] = f2bf(f0.z); t.u[3] = f2bf(f0.w);
  t.u[4] = f2bf(f1.x); t.u[5] = f2bf(f1.y); t.u[6] = f2bf(f1.z); t.u[7] = f2bf(f1.w);
  return t.b;
}

#define GLDS(gptr, lptr) \
  __builtin_amdgcn_global_load_lds((const __attribute__((address_space(1))) u32*)(gptr), \
                                   (__attribute__((address_space(3))) u32*)(lptr), 16, 0, 0)

#define LOGITS_N 67108864

// ---------------- proj GEMM body (shared by prep branches) ----------------
__device__ __forceinline__ void proj_body(const float* __restrict__ A,
                                          const float* __restrict__ Bw,
                                          const float* __restrict__ bias,
                                          float* __restrict__ C,
                                          int m0, int n0, int N, int K,
                                          float (*red)[64][64]) {
  int tid = threadIdx.x;
  int lane = tid & 63, wid = tid >> 6;
  int kper = K >> 2;
  int kbase = wid * kper;
  int ksteps = kper >> 5;
  int r16 = lane & 15, khi = (lane >> 4) * 8;

  f32x4 z = {0.f, 0.f, 0.f, 0.f};
  f32x4 acc[4][4];
  for (int i = 0; i < 4; ++i)
    for (int j = 0; j < 4; ++j) acc[i][j] = z;

  for (int ks = 0; ks < ksteps; ++ks) {
    int k = kbase + ks * 32 + khi;
    bf16x8 af[4], bf[4];
#pragma unroll
    for (int fm = 0; fm < 4; ++fm)
      af[fm] = load_cvt8(A + (size_t)(m0 + fm * 16 + r16) * K + k);
#pragma unroll
    for (int fn = 0; fn < 4; ++fn)
      bf[fn] = load_cvt8(Bw + (size_t)(n0 + fn * 16 + r16) * K + k);
#pragma unroll
    for (int fm = 0; fm < 4; ++fm)
#pragma unroll
      for (int fn = 0; fn < 4; ++fn)
        acc[fm][fn] = __builtin_amdgcn_mfma_f32_16x16x32_bf16(af[fm], bf[fn], acc[fm][fn], 0, 0, 0);
  }

#pragma unroll
  for (int fm = 0; fm < 4; ++fm)
#pragma unroll
    for (int fn = 0; fn < 4; ++fn)
#pragma unroll
      for (int i = 0; i < 4; ++i)
        red[wid][fm * 16 + (lane >> 4) * 4 + i][fn * 16 + r16] = acc[fm][fn][i];
  __syncthreads();
  for (int idx = tid; idx < 4096; idx += 256) {
    int r = idx >> 6, c = idx & 63;
    float s = red[0][r][c] + red[1][r][c] + red[2][r][c] + red[3][r][c] + bias[n0 + c];
    C[(size_t)(m0 + r) * N + n0 + c] = s;
  }
}

// ---------------- prep: conv_v4 + conv_wdur + proj_enc + proj_pred in one launch ----------------
// blocks [0,640): W_out->bf16; [640,680): W_dur->padded bf16; [680,840): enc proj; [840,880): pred proj
__global__ __launch_bounds__(256) void prep(const float* __restrict__ W_out, u16* __restrict__ WoB,
                                            const float* __restrict__ W_dur, u16* __restrict__ WdB,
                                            const float* __restrict__ encoder,
                                            const float* __restrict__ W_enc, const float* __restrict__ b_enc,
                                            float* __restrict__ encP,
                                            const float* __restrict__ predictor,
                                            const float* __restrict__ W_pred, const float* __restrict__ b_pred,
                                            float* __restrict__ predP) {
  __shared__ float red[4][64][64];
  int bx = blockIdx.x;
  int tid = threadIdx.x;
  if (bx < 640) {
    int i = bx * 256 + tid;   // < 163840
    float4 f = ((const float4*)W_out)[i];
    union { u16 u[4]; int2 v; } o;
    o.u[0] = f2bf(f.x); o.u[1] = f2bf(f.y); o.u[2] = f2bf(f.z); o.u[3] = f2bf(f.w);
    ((int2*)WoB)[i] = o.v;
  } else if (bx < 680) {
    int i = (bx - 640) * 256 + tid;
    if (i < 16 * 640) WdB[i] = (i < 5 * 640) ? f2bf(W_dur[i]) : (u16)0;
  } else if (bx < 840) {
    int idx = bx - 680;
    proj_body(encoder, W_enc, b_enc, encP, (idx / 10) * 64, (idx % 10) * 64, 640, 1024, red);
  } else {
    int idx = bx - 840;
    proj_body(predictor, W_pred, b_pred, predP, (idx / 10) * 64, (idx % 10) * 64, 640, 640, red);
  }
}

// ---------------- joint = tanh(enc + pred) -> bf16 (verified ~17 us) ----------------
__global__ __launch_bounds__(256) void joint_tanh(const float* __restrict__ enc,
                                                  const float* __restrict__ pred,
                                                  u16* __restrict__ J) {
  const int total = 65536 * 80;
  for (int c = blockIdx.x * 256 + threadIdx.x; c < total; c += gridDim.x * 256) {
    int m = c / 80;
    int j = c - m * 80;
    int bt = m >> 6;
    int uu = m & 63;
    int b = bt >> 8;
    const float* ep = enc + bt * 640 + j * 8;
    const float* pp = pred + (b * 64 + uu) * 640 + j * 8;
    float4 e0 = *(const float4*)ep;
    float4 e1 = *(const float4*)(ep + 4);
    float4 p0 = *(const float4*)pp;
    float4 p1 = *(const float4*)(pp + 4);
    union { u16 u[8]; int4 v; } o;
    o.u[0] = f2bf(tanh_fast(e0.x + p0.x));
    o.u[1] = f2bf(tanh_fast(e0.y + p0.y));
    o.u[2] = f2bf(tanh_fast(e0.z + p0.z));
    o.u[3] = f2bf(tanh_fast(e0.w + p0.w));
    o.u[4] = f2bf(tanh_fast(e1.x + p1.x));
    o.u[5] = f2bf(tanh_fast(e1.y + p1.y));
    o.u[6] = f2bf(tanh_fast(e1.z + p1.z));
    o.u[7] = f2bf(tanh_fast(e1.w + p1.w));
    *(int4*)(J + (size_t)c * 8) = o.v;
  }
}

// ---------------- main GEMM: BM=128 x BN=256, 48KB single-buffer, T2 swizzle, 3 blocks/CU ----------------
// 512 thr / 8 waves (2 wr x 4 wc), wave = 64x64, acc = 64 VGPR. B-staging traffic halved vs 128x128.
// J [65536][640] bf16, Wo [1024][640] bf16, Wd [16][640] bf16 (rows>=5 zero)
// out: logits f32 [65536][1024] at 0, durations f32 [65536][5] at 67108864

// One 64-row x 64-col staging pass (8 KB, 512 thr x 16B).
// LDS phys (row, chunk) holds logical (row, chunk ^ (row&7))  [T2 swizzle, 8-u16 chunks]
__device__ __forceinline__ void stage64(const u16* __restrict__ g, u16* l,
                                        int wid, int lane) {
  int rl = wid * 8 + (lane >> 3);           // 0..63 (8 waves x 8 rows)
  int cl = ((lane & 7) ^ (lane >> 3)) * 8;  // pre-swizzled source column
  GLDS(g + (size_t)rl * 640 + cl, l + wid * 512);
}

__global__ __launch_bounds__(512, 6) void main_gemm(const u16* __restrict__ J,
                                                    const u16* __restrict__ Wo,
                                                    const u16* __restrict__ Wd,
                                                    const float* __restrict__ b_out,
                                                    const float* __restrict__ b_dur,
                                                    float* __restrict__ out) {
  __shared__ __align__(16) u16 As[8192];    // 128 x 64 = 16 KB
  __shared__ __align__(16) u16 Bs[16384];   // 256 x 64 = 32 KB  -> 48 KB total
  int tid = threadIdx.x;
  int lane = tid & 63, wid = tid >> 6;
  int bid = blockIdx.x;
  // XCD swizzle: 2048 % 8 == 0 bijective; bn fastest -> A-strip L2 reuse on-XCD
  int swz = (bid & 7) * 256 + (bid >> 3);
  int bn = swz & 3, bm = swz >> 2;
  int m0 = bm * 128, n0 = bn * 256;
  int wr = wid >> 2, wc = wid & 3;
  int r16 = lane & 15, khi = (lane >> 4) * 8;
  int xorv = (r16 & 7) << 3;
  bool do_dur = (bn == 0) && (wc == 0);

  f32x4 z = {0.f, 0.f, 0.f, 0.f};
  f32x4 acc[4][4];
#pragma unroll
  for (int i = 0; i < 4; ++i)
#pragma unroll
    for (int j = 0; j < 4; ++j) acc[i][j] = z;
  f32x4 dacc[4] = {z, z, z, z};

  const u16* Jb = J + (size_t)m0 * 640;
  const u16* Wb = Wo + (size_t)n0 * 640;

  for (int t = 0; t < 10; ++t) {
    stage64(Jb + t * 64, As, wid, lane);
    stage64(Jb + (size_t)64 * 640 + t * 64, As + 4096, wid, lane);
    stage64(Wb + t * 64, Bs, wid, lane);
    stage64(Wb + (size_t)64 * 640 + t * 64, Bs + 4096, wid, lane);
    stage64(Wb + (size_t)128 * 640 + t * 64, Bs + 8192, wid, lane);
    stage64(Wb + (size_t)192 * 640 + t * 64, Bs + 12288, wid, lane);
    __syncthreads();  // compiler drains vmcnt(0) before s_barrier -> GLDS landed
#pragma unroll
    for (int ks = 0; ks < 2; ++ks) {
      int cks = (ks * 32 + khi) ^ xorv;
      FragI af[4], bfr[4], wd;
#pragma unroll
      for (int fn = 0; fn < 4; ++fn)
        bfr[fn].i = *(const int4*)(Bs + (wc * 64 + fn * 16 + r16) * 64 + cks);
#pragma unroll
      for (int fm = 0; fm < 4; ++fm)
        af[fm].i = *(const int4*)(As + (wr * 64 + fm * 16 + r16) * 64 + cks);
      if (do_dur)
        wd.i = *(const int4*)(Wd + (size_t)r16 * 640 + t * 64 + ks * 32 + khi);
#pragma unroll
      for (int fm = 0; fm < 4; ++fm) {
#pragma unroll
        for (int fn = 0; fn < 4; ++fn)
          acc[fm][fn] = __builtin_amdgcn_mfma_f32_16x16x32_bf16(af[fm].b, bfr[fn].b, acc[fm][fn], 0, 0, 0);
        if (do_dur)
          dacc[fm] = __builtin_amdgcn_mfma_f32_16x16x32_bf16(af[fm].b, wd.b, dacc[fm], 0, 0, 0);
      }
    }
    __syncthreads();  // all waves done reading before next stage overwrites
  }

  // epilogue
  int rb = m0 + wr * 64 + (lane >> 4) * 4;
  int cb = n0 + wc * 64 + r16;
#pragma unroll
  for (int fn = 0; fn < 4; ++fn) {
    int col = cb + fn * 16;
    float bo = b_out[col];
#pragma unroll
    for (int fm = 0; fm < 4; ++fm) {
      int row = rb + fm * 16;
#pragma unroll
      for (int i = 0; i < 4; ++i)
        out[(size_t)(row + i) * 1024 + col] = acc[fm][fn][i] + bo;
    }
  }
  if (do_dur && r16 < 5) {
    float bd = b_dur[r16];
#pragma unroll
    for (int fm = 0; fm < 4; ++fm) {
      int row = rb + fm * 16;
#pragma unroll
      for (int i = 0; i < 4; ++i)
        out[LOGITS_N + (size_t)(row + i) * 5 + r16] = dacc[fm][i] + bd;
    }
  }
}

extern "C" void kernel_launch(void* const* d_in, const int* in_sizes, int n_in,
                              void* d_out, int out_size, void* d_ws, size_t ws_size,
                              hipStream_t stream) {
  const float* encoder   = (const float*)d_in[0];
  const float* predictor = (const float*)d_in[1];
  const float* W_enc = (const float*)d_in[2];
  const float* b_enc = (const float*)d_in[3];
  const float* W_pred = (const float*)d_in[4];
  const float* b_pred = (const float*)d_in[5];
  const float* W_out = (const float*)d_in[6];
  const float* b_out = (const float*)d_in[7];
  const float* W_dur = (const float*)d_in[8];
  const float* b_dur = (const float*)d_in[9];
  float* out = (float*)d_out;

  char* ws = (char*)d_ws;
  u16* Jbuf    = (u16*)(ws);                   // 65536*640*2 = 83,886,080 B
  u16* WoutB   = (u16*)(ws + 83886080);        // 1024*640*2  =  1,310,720 B
  u16* WdurB   = (u16*)(ws + 85196800);        // 16*640*2    =     20,480 B
  float* encP  = (float*)(ws + 85217280);      // 1024*640*4  =  2,621,440 B
  float* predP = (float*)(ws + 87838720);      // 256*640*4   =    655,360 B

  prep<<<880, 256, 0, stream>>>(W_out, WoutB, W_dur, WdurB,
                                encoder, W_enc, b_enc, encP,
                                predictor, W_pred, b_pred, predP);
  joint_tanh<<<2048, 256, 0, stream>>>(encP, predP, Jbuf);
  main_gemm<<<2048, 512, 0, stream>>>(Jbuf, WoutB, WdurB, b_out, b_dur, out);
}

// Round 13
// 172.208 us; speedup vs baseline: 5.7923x; 5.7923x over previous
//
#include <hip/hip_runtime.h>

typedef unsigned short u16;
typedef unsigned int u32;

typedef __bf16 bf16x8 __attribute__((ext_vector_type(8)));
typedef float f32x4 __attribute__((ext_vector_type(4)));

union FragI { int4 i; bf16x8 b; u16 u[8]; };

__device__ __forceinline__ u16 f2bf(float x) {
  u32 u = __float_as_uint(x);
  u32 r = (u + 0x7fffu + ((u >> 16) & 1u)) >> 16;
  return (u16)r;
}
__device__ __forceinline__ float tanh_fast(float x) {
  float e = __expf(2.0f * x);
  return 1.0f - __fdividef(2.0f, e + 1.0f);
}
__device__ __forceinline__ bf16x8 load_cvt8(const float* __restrict__ p) {
  float4 f0 = *(const float4*)p;
  float4 f1 = *(const float4*)(p + 4);
  union { bf16x8 b; u16 u[8]; } t;
  t.u[0] = f2bf(f0.x); t.u[1] = f2bf(f0.y); t.u[2] = f2bf(f0.z); t.u[3] = f2bf(f0.w);
  t.u[4] = f2bf(f1.x); t.u[5] = f2bf(f1.y); t.u[6] = f2bf(f1.z); t.u[7] = f2bf(f1.w);
  return t.b;
}

#define GLDS(gptr, lptr) \
  __builtin_amdgcn_global_load_lds((const __attribute__((address_space(1))) u32*)(gptr), \
                                   (__attribute__((address_space(3))) u32*)(lptr), 16, 0, 0)

#define LOGITS_N 67108864

// ---------------- proj GEMM body (shared by prep branches; verified R1-R12) ----------------
__device__ __forceinline__ void proj_body(const float* __restrict__ A,
                                          const float* __restrict__ Bw,
                                          const float* __restrict__ bias,
                                          float* __restrict__ C,
                                          int m0, int n0, int N, int K,
                                          float (*red)[64][64]) {
  int tid = threadIdx.x;
  int lane = tid & 63, wid = tid >> 6;
  int kper = K >> 2;
  int kbase = wid * kper;
  int ksteps = kper >> 5;
  int r16 = lane & 15, khi = (lane >> 4) * 8;

  f32x4 z = {0.f, 0.f, 0.f, 0.f};
  f32x4 acc[4][4];
  for (int i = 0; i < 4; ++i)
    for (int j = 0; j < 4; ++j) acc[i][j] = z;

  for (int ks = 0; ks < ksteps; ++ks) {
    int k = kbase + ks * 32 + khi;
    bf16x8 af[4], bf[4];
#pragma unroll
    for (int fm = 0; fm < 4; ++fm)
      af[fm] = load_cvt8(A + (size_t)(m0 + fm * 16 + r16) * K + k);
#pragma unroll
    for (int fn = 0; fn < 4; ++fn)
      bf[fn] = load_cvt8(Bw + (size_t)(n0 + fn * 16 + r16) * K + k);
#pragma unroll
    for (int fm = 0; fm < 4; ++fm)
#pragma unroll
      for (int fn = 0; fn < 4; ++fn)
        acc[fm][fn] = __builtin_amdgcn_mfma_f32_16x16x32_bf16(af[fm], bf[fn], acc[fm][fn], 0, 0, 0);
  }

#pragma unroll
  for (int fm = 0; fm < 4; ++fm)
#pragma unroll
    for (int fn = 0; fn < 4; ++fn)
#pragma unroll
      for (int i = 0; i < 4; ++i)
        red[wid][fm * 16 + (lane >> 4) * 4 + i][fn * 16 + r16] = acc[fm][fn][i];
  __syncthreads();
  for (int idx = tid; idx < 4096; idx += 256) {
    int r = idx >> 6, c = idx & 63;
    float s = red[0][r][c] + red[1][r][c] + red[2][r][c] + red[3][r][c] + bias[n0 + c];
    C[(size_t)(m0 + r) * N + n0 + c] = s;
  }
}

// ---------------- prep: conv_v4 + conv_wdur + proj_enc + proj_pred in one launch ----------------
// blocks [0,640): W_out->bf16; [640,680): W_dur->padded bf16; [680,840): enc proj; [840,880): pred proj
__global__ __launch_bounds__(256) void prep(const float* __restrict__ W_out, u16* __restrict__ WoB,
                                            const float* __restrict__ W_dur, u16* __restrict__ WdB,
                                            const float* __restrict__ encoder,
                                            const float* __restrict__ W_enc, const float* __restrict__ b_enc,
                                            float* __restrict__ encP,
                                            const float* __restrict__ predictor,
                                            const float* __restrict__ W_pred, const float* __restrict__ b_pred,
                                            float* __restrict__ predP) {
  __shared__ float red[4][64][64];
  int bx = blockIdx.x;
  int tid = threadIdx.x;
  if (bx < 640) {
    int i = bx * 256 + tid;   // < 163840
    float4 f = ((const float4*)W_out)[i];
    union { u16 u[4]; int2 v; } o;
    o.u[0] = f2bf(f.x); o.u[1] = f2bf(f.y); o.u[2] = f2bf(f.z); o.u[3] = f2bf(f.w);
    ((int2*)WoB)[i] = o.v;
  } else if (bx < 680) {
    int i = (bx - 640) * 256 + tid;
    if (i < 16 * 640) WdB[i] = (i < 5 * 640) ? f2bf(W_dur[i]) : (u16)0;
  } else if (bx < 840) {
    int idx = bx - 680;
    proj_body(encoder, W_enc, b_enc, encP, (idx / 10) * 64, (idx % 10) * 64, 640, 1024, red);
  } else {
    int idx = bx - 840;
    proj_body(predictor, W_pred, b_pred, predP, (idx / 10) * 64, (idx % 10) * 64, 640, 640, red);
  }
}

// ---------------- joint = tanh(enc + pred) -> bf16 (verified ~17 us) ----------------
__global__ __launch_bounds__(256) void joint_tanh(const float* __restrict__ enc,
                                                  const float* __restrict__ pred,
                                                  u16* __restrict__ J) {
  const int total = 65536 * 80;
  for (int c = blockIdx.x * 256 + threadIdx.x; c < total; c += gridDim.x * 256) {
    int m = c / 80;
    int j = c - m * 80;
    int bt = m >> 6;
    int uu = m & 63;
    int b = bt >> 8;
    const float* ep = enc + bt * 640 + j * 8;
    const float* pp = pred + (b * 64 + uu) * 640 + j * 8;
    float4 e0 = *(const float4*)ep;
    float4 e1 = *(const float4*)(ep + 4);
    float4 p0 = *(const float4*)pp;
    float4 p1 = *(const float4*)(pp + 4);
    union { u16 u[8]; int4 v; } o;
    o.u[0] = f2bf(tanh_fast(e0.x + p0.x));
    o.u[1] = f2bf(tanh_fast(e0.y + p0.y));
    o.u[2] = f2bf(tanh_fast(e0.z + p0.z));
    o.u[3] = f2bf(tanh_fast(e0.w + p0.w));
    o.u[4] = f2bf(tanh_fast(e1.x + p1.x));
    o.u[5] = f2bf(tanh_fast(e1.y + p1.y));
    o.u[6] = f2bf(tanh_fast(e1.z + p1.z));
    o.u[7] = f2bf(tanh_fast(e1.w + p1.w));
    *(int4*)(J + (size_t)c * 8) = o.v;
  }
}

// ---------------- main GEMM: R8-exact — 128x128, 32KB single-buffer, T2 swizzle,
// (256,3) launch bounds, fused durations; best-measured config (main ~135 us) ----------------
// J [65536][640] bf16, Wo [1024][640] bf16, Wd [16][640] bf16 (rows>=5 zero)
// out: logits f32 [65536][1024] at 0, durations f32 [65536][5] at 67108864

// Stage one 128x64 bf16 tile (16 KB): 4 x GLDS(16B) per thread (256 thr).
// LDS phys (row, chunk) holds logical (row, chunk ^ (row&7))  [T2 swizzle, 8-u16 chunks]
__device__ __forceinline__ void stage128(const u16* __restrict__ g, u16* l,
                                         int wid, int lane) {
  int rl = wid * 8 + (lane >> 3);
  int cl = ((lane & 7) ^ (lane >> 3)) * 8;
  const u16* gp = g + (size_t)rl * 640 + cl;
  u16* lp = l + wid * 512;
#pragma unroll
  for (int j = 0; j < 4; ++j)
    GLDS(gp + (size_t)j * 32 * 640, lp + j * 2048);
}

__global__ __launch_bounds__(256, 3) void main_gemm(const u16* __restrict__ J,
                                                    const u16* __restrict__ Wo,
                                                    const u16* __restrict__ Wd,
                                                    const float* __restrict__ b_out,
                                                    const float* __restrict__ b_dur,
                                                    float* __restrict__ out) {
  __shared__ __align__(16) u16 As[8192];   // 16 KB (128 x 64)
  __shared__ __align__(16) u16 Bs[8192];   // 16 KB  -> 32 KB total
  int tid = threadIdx.x;
  int lane = tid & 63, wid = tid >> 6;
  int bid = blockIdx.x;
  // XCD-aware swizzle: 4096 % 8 == 0 bijective; bn fastest -> A-strip L2 reuse on-XCD
  int swz = (bid & 7) * 512 + (bid >> 3);
  int bn = swz & 7, bm = swz >> 3;
  int m0 = bm * 128, n0 = bn * 128;
  int wr = wid >> 1, wc = wid & 1;
  int r16 = lane & 15, khi = (lane >> 4) * 8;
  int xorv = (r16 & 7) << 3;
  bool do_dur = (bn == 0);

  f32x4 z = {0.f, 0.f, 0.f, 0.f};
  f32x4 acc[4][4];
#pragma unroll
  for (int i = 0; i < 4; ++i)
#pragma unroll
    for (int j = 0; j < 4; ++j) acc[i][j] = z;
  f32x4 dacc[4] = {z, z, z, z};

  const u16* Jb = J + (size_t)m0 * 640;
  const u16* Wb = Wo + (size_t)n0 * 640;

  for (int t = 0; t < 10; ++t) {
    stage128(Jb + t * 64, As, wid, lane);
    stage128(Wb + t * 64, Bs, wid, lane);
    __syncthreads();  // compiler drains vmcnt(0) before s_barrier -> GLDS landed
#pragma unroll
    for (int ks = 0; ks < 2; ++ks) {
      int cks = (ks * 32 + khi) ^ xorv;
      FragI af[4], bfr[4], wd;
#pragma unroll
      for (int fn = 0; fn < 4; ++fn)
        bfr[fn].i = *(const int4*)(Bs + (wc * 64 + fn * 16 + r16) * 64 + cks);
#pragma unroll
      for (int fm = 0; fm < 4; ++fm)
        af[fm].i = *(const int4*)(As + (wr * 64 + fm * 16 + r16) * 64 + cks);
      if (do_dur)
        wd.i = *(const int4*)(Wd + (size_t)r16 * 640 + t * 64 + ks * 32 + khi);
#pragma unroll
      for (int fm = 0; fm < 4; ++fm) {
#pragma unroll
        for (int fn = 0; fn < 4; ++fn)
          acc[fm][fn] = __builtin_amdgcn_mfma_f32_16x16x32_bf16(af[fm].b, bfr[fn].b, acc[fm][fn], 0, 0, 0);
        if (do_dur)
          dacc[fm] = __builtin_amdgcn_mfma_f32_16x16x32_bf16(af[fm].b, wd.b, dacc[fm], 0, 0, 0);
      }
    }
    __syncthreads();  // all waves done reading before next stage overwrites
  }

  // epilogue
  int rb = m0 + wr * 64 + (lane >> 4) * 4;
  int cb = n0 + wc * 64 + r16;
#pragma unroll
  for (int fn = 0; fn < 4; ++fn) {
    int col = cb + fn * 16;
    float bo = b_out[col];
#pragma unroll
    for (int fm = 0; fm < 4; ++fm) {
      int row = rb + fm * 16;
#pragma unroll
      for (int i = 0; i < 4; ++i)
        out[(size_t)(row + i) * 1024 + col] = acc[fm][fn][i] + bo;
    }
  }
  if (do_dur && r16 < 5) {
    float bd = b_dur[r16];
#pragma unroll
    for (int fm = 0; fm < 4; ++fm) {
      int row = rb + fm * 16;
#pragma unroll
      for (int i = 0; i < 4; ++i)
        out[LOGITS_N + (size_t)(row + i) * 5 + r16] = dacc[fm][i] + bd;
    }
  }
}

extern "C" void kernel_launch(void* const* d_in, const int* in_sizes, int n_in,
                              void* d_out, int out_size, void* d_ws, size_t ws_size,
                              hipStream_t stream) {
  const float* encoder   = (const float*)d_in[0];
  const float* predictor = (const float*)d_in[1];
  const float* W_enc = (const float*)d_in[2];
  const float* b_enc = (const float*)d_in[3];
  const float* W_pred = (const float*)d_in[4];
  const float* b_pred = (const float*)d_in[5];
  const float* W_out = (const float*)d_in[6];
  const float* b_out = (const float*)d_in[7];
  const float* W_dur = (const float*)d_in[8];
  const float* b_dur = (const float*)d_in[9];
  float* out = (float*)d_out;

  char* ws = (char*)d_ws;
  u16* Jbuf    = (u16*)(ws);                   // 65536*640*2 = 83,886,080 B
  u16* WoutB   = (u16*)(ws + 83886080);        // 1024*640*2  =  1,310,720 B
  u16* WdurB   = (u16*)(ws + 85196800);        // 16*640*2    =     20,480 B
  float* encP  = (float*)(ws + 85217280);      // 1024*640*4  =  2,621,440 B
  float* predP = (float*)(ws + 87838720);      // 256*640*4   =    655,360 B

  prep<<<880, 256, 0, stream>>>(W_out, WoutB, W_dur, WdurB,
                                encoder, W_enc, b_enc, encP,
                                predictor, W_pred, b_pred, predP);
  joint_tanh<<<2048, 256, 0, stream>>>(encP, predP, Jbuf);
  main_gemm<<<4096, 256, 0, stream>>>(Jbuf, WoutB, WdurB, b_out, b_dur, out);
}